// Round 7
// baseline (140.882 us; speedup 1.0000x reference)
//
#include <hip/hip_runtime.h>
#include <hip/hip_bf16.h>

// Problem constants
#define BB 2
#define SS 2048
#define DD 1024
#define HH 16
#define MMR (BB*SS)   // 4096 rows
#define ND3 3072      // fused QKV width

typedef __hip_bfloat16 bf;
typedef __bf16 bf16x8 __attribute__((ext_vector_type(8)));
typedef float f32x4 __attribute__((ext_vector_type(4)));
typedef float f32x16 __attribute__((ext_vector_type(16)));

#define VMCNT(n) asm volatile("s_waitcnt vmcnt(" #n ")" ::: "memory")

__device__ __forceinline__ f32x4 mfma16(bf16x8 a, bf16x8 b, f32x4 c) {
    return __builtin_amdgcn_mfma_f32_16x16x32_bf16(a, b, c, 0, 0, 0);
}
__device__ __forceinline__ f32x16 mfma32(bf16x8 a, bf16x8 b, f32x16 c) {
    return __builtin_amdgcn_mfma_f32_32x32x16_bf16(a, b, c, 0, 0, 0);
}
__device__ __forceinline__ unsigned cvt_pk_bf16(float lo, float hi) {
    unsigned r;
    asm("v_cvt_pk_bf16_f32 %0, %1, %2" : "=v"(r) : "v"(lo), "v"(hi));
    return r;
}
// after: a = {a.lo31, b.lo31}, b = {a.hi31, b.hi31}
__device__ __forceinline__ void pl32swap(unsigned& a, unsigned& b) {
    asm("v_permlane32_swap_b32 %0, %1" : "+v"(a), "+v"(b));
}
// async global->LDS, 16B/lane; LDS dest = wave-uniform base + lane*16
__device__ __forceinline__ void glds16(const bf* g, bf* l) {
    __builtin_amdgcn_global_load_lds(
        (const __attribute__((address_space(1))) void*)g,
        (__attribute__((address_space(3))) void*)l,
        16, 0, 0);
}

// ---------------------------------------------------------------
// All f32->bf16 converts in ONE launch. blocks 0..4095: X (4M elems);
// blocks 4096..8191: Wq,Wk,Wv (into Wqkv) and Wo (into Wob), 1M each.
__global__ __launch_bounds__(256) void k_convert(const float* __restrict__ X,
                                                 const float* __restrict__ Wq,
                                                 const float* __restrict__ Wk,
                                                 const float* __restrict__ Wv,
                                                 const float* __restrict__ Wo,
                                                 bf* __restrict__ Xb,
                                                 bf* __restrict__ Wqkv,
                                                 bf* __restrict__ Wob) {
    const int bid = blockIdx.x;
    const float* src;
    bf* dst;
    int off;
    if (bid < 4096) {
        src = X; dst = Xb; off = bid;
    } else {
        const int r = (bid - 4096) >> 10;
        src = (r == 0) ? Wq : (r == 1) ? Wk : (r == 2) ? Wv : Wo;
        dst = (r < 3) ? (Wqkv + (size_t)r * 1048576) : Wob;
        off = (bid - 4096) & 1023;
    }
    const int j = (off * 256 + threadIdx.x) * 4;
    float4 v = *(const float4*)(src + j);
    bf tmp[4];
    tmp[0] = __float2bfloat16(v.x);
    tmp[1] = __float2bfloat16(v.y);
    tmp[2] = __float2bfloat16(v.z);
    tmp[3] = __float2bfloat16(v.w);
    *(uint2*)(dst + j) = *(const uint2*)tmp;
}

// ---------------------------------------------------------------
// QKV GEMM: 128x128 tile, BK=32, **8 waves (512 thr)**, wave = 32x64 quadrant
// (wr=(w>>1)*32, wc=(w&1)*64, 8 MFMA/step). 3-buffer LDS pipeline, counted
// vmcnt (2 glds/thread/stage), raw s_barrier, seg-XOR LDS swizzle (0-conflict,
// r6-verified). 768 blocks x 8 waves = 24 waves/CU (75% occupancy ceiling).
// Fused epilogue: cols<2048 -> per-head L2-norm * mask -> Qn/Kn [B*H,S,64];
// cols>=2048 -> transposed bf16 write to Vt [B*H,64,S].
__global__ __launch_bounds__(512, 6) void k_gemm8(const bf* __restrict__ A,
                                                  const bf* __restrict__ Bt,
                                                  const int* __restrict__ masks,
                                                  bf* __restrict__ Qn,
                                                  bf* __restrict__ Kn,
                                                  bf* __restrict__ Vt,
                                                  int nx, int K) {
    __shared__ __align__(16) bf Asm[3][128 * 32];
    __shared__ __align__(16) bf Bsm[3][128 * 32];
    const int tid = threadIdx.x;
    const int w = tid >> 6, lane = tid & 63, g = lane >> 4, rl = lane & 15;
    const int cpx = gridDim.x >> 3;
    const int swz = (blockIdx.x & 7) * cpx + (blockIdx.x >> 3);
    const int m0 = (swz / nx) * 128, n0 = (swz % nx) * 128;
    const int wr = (w >> 1) * 32, wc = (w & 1) * 64;
    const int lrow = lane >> 2, lseg = lane & 3;
    const int xseg = lseg ^ ((lrow >> 1) & 3);   // pre-swizzled source seg

    f32x4 acc[2][4] = {};
    const bf* Ap = A + (size_t)m0 * K;
    const bf* Bp = Bt + (size_t)n0 * K;

    auto stage = [&](int bi, int k0) {
        glds16(Ap + (size_t)(w * 16 + lrow) * K + k0 + xseg * 8, &Asm[bi][w * 512]);
        glds16(Bp + (size_t)(w * 16 + lrow) * K + k0 + xseg * 8, &Bsm[bi][w * 512]);
    };

    const int T = K >> 5;
    stage(0, 0);
    stage(1, 32);
    int cur = 0, nxt = 2;
    for (int t = 0; t < T; ++t) {
        __builtin_amdgcn_sched_barrier(0);
        if (t < T - 1) { VMCNT(2); } else { VMCNT(0); }
        __builtin_amdgcn_s_barrier();     // staged loads stay in flight
        __builtin_amdgcn_sched_barrier(0);
        if (t + 2 < T) stage(nxt, (t + 2) * 32);

        const bf* Ab = Asm[cur];
        const bf* Bb = Bsm[cur];
        bf16x8 af[2], bfr[4];
#pragma unroll
        for (int m = 0; m < 2; ++m) {
            const int row = wr + m * 16 + rl;
            af[m] = __builtin_bit_cast(bf16x8,
                *(const int4*)&Ab[row * 32 + (g ^ ((row >> 1) & 3)) * 8]);
        }
#pragma unroll
        for (int n = 0; n < 4; ++n) {
            const int row = wc + n * 16 + rl;
            bfr[n] = __builtin_bit_cast(bf16x8,
                *(const int4*)&Bb[row * 32 + (g ^ ((row >> 1) & 3)) * 8]);
        }
        __builtin_amdgcn_s_setprio(1);
#pragma unroll
        for (int m = 0; m < 2; ++m)
#pragma unroll
            for (int n = 0; n < 4; ++n)
                acc[m][n] = mfma16(af[m], bfr[n], acc[m][n]);
        __builtin_amdgcn_s_setprio(0);

        cur = (cur == 2) ? 0 : cur + 1;
        nxt = (nxt == 2) ? 0 : nxt + 1;
    }

    const int ncol0 = n0 + wc;   // wave's 64-col base == one head slice
    if (ncol0 < 2048) {
        bf* dst = (ncol0 < 1024) ? Qn : Kn;
        const int h2 = (ncol0 >> 6) & 15;
#pragma unroll
        for (int m = 0; m < 2; ++m) {
#pragma unroll
            for (int ri = 0; ri < 4; ++ri) {
                const int row = m0 + wr + m * 16 + g * 4 + ri;   // b*S+s
                float ss = 0.f;
#pragma unroll
                for (int n = 0; n < 4; ++n) ss += acc[m][n][ri] * acc[m][n][ri];
#pragma unroll
                for (int d = 1; d < 16; d <<= 1) ss += __shfl_xor(ss, d, 64);
                const float sc = rsqrtf(ss) * (masks[row] ? 1.0f : 0.0f);
                const int b = row >> 11, s = row & 2047;
                const size_t base = ((size_t)(b * HH + h2) * SS + s) * 64;
#pragma unroll
                for (int n = 0; n < 4; ++n)
                    dst[base + n * 16 + rl] = __float2bfloat16(acc[m][n][ri] * sc);
            }
        }
    } else {
        // fused V transpose: Vt[(b*H+h)*64 + d][s], packed 4-bf16 writes
        const int h2 = (ncol0 - 2048) >> 6;
        const int b = (m0 + wr) >> 11;
        const int sb = ((m0 + wr) & 2047) + g * 4;
#pragma unroll
        for (int m = 0; m < 2; ++m)
#pragma unroll
            for (int n = 0; n < 4; ++n) {
                const int d = n * 16 + rl;
                bf t4[4];
#pragma unroll
                for (int ri = 0; ri < 4; ++ri) t4[ri] = __float2bfloat16(acc[m][n][ri]);
                *(uint2*)&Vt[((size_t)(b * HH + h2) * 64 + d) * SS + sb + m * 16] =
                    *(uint2*)t4;
            }
    }
}

// ---------------------------------------------------------------
// Out-proj GEMM: 64x128 tile, BK=32, 4 waves, 3-buffer counted-vmcnt pipeline
// (r6-verified), f32 out.
__global__ __launch_bounds__(256) void k_gemm(const bf* __restrict__ A,
                                              const bf* __restrict__ Bt,
                                              float* __restrict__ Cf,
                                              int nx, int N, int K) {
    constexpr int BM = 64, BN = 128;
    __shared__ __align__(16) bf Asm[3][BM * 32];
    __shared__ __align__(16) bf Bsm[3][BN * 32];
    const int tid = threadIdx.x;
    const int w = tid >> 6, lane = tid & 63, g = lane >> 4, rl = lane & 15;
    const int cpx = gridDim.x >> 3;
    const int swz = (blockIdx.x & 7) * cpx + (blockIdx.x >> 3);
    const int m0 = (swz / nx) * BM, n0 = (swz % nx) * BN;
    const int wr = (w >> 1) * 32, wc = (w & 1) * 64;
    const int lrow = lane >> 2, lseg = lane & 3;
    const int xseg = lseg ^ ((lrow >> 1) & 3);

    f32x4 acc[2][4] = {};
    const bf* Ap = A + (size_t)m0 * K;
    const bf* Bp = Bt + (size_t)n0 * K;

    auto stage = [&](int bi, int k0) {
        glds16(Ap + (size_t)(w * 16 + lrow) * K + k0 + xseg * 8, &Asm[bi][w * 512]);
#pragma unroll
        for (int u = 0; u < 2; ++u)
            glds16(Bp + (size_t)(u * 64 + w * 16 + lrow) * K + k0 + xseg * 8,
                   &Bsm[bi][(u * 64 + w * 16) * 32]);
    };

    const int T = K >> 5;
    stage(0, 0);
    stage(1, 32);
    int cur = 0, nxt = 2;
    for (int t = 0; t < T; ++t) {
        __builtin_amdgcn_sched_barrier(0);
        if (t < T - 1) { VMCNT(3); } else { VMCNT(0); }
        __builtin_amdgcn_s_barrier();
        __builtin_amdgcn_sched_barrier(0);
        if (t + 2 < T) stage(nxt, (t + 2) * 32);

        const bf* Ab = Asm[cur];
        const bf* Bb = Bsm[cur];
        bf16x8 af[2], bfr[4];
#pragma unroll
        for (int m = 0; m < 2; ++m) {
            const int row = wr + m * 16 + rl;
            af[m] = __builtin_bit_cast(bf16x8,
                *(const int4*)&Ab[row * 32 + (g ^ ((row >> 1) & 3)) * 8]);
        }
#pragma unroll
        for (int n = 0; n < 4; ++n) {
            const int row = wc + n * 16 + rl;
            bfr[n] = __builtin_bit_cast(bf16x8,
                *(const int4*)&Bb[row * 32 + (g ^ ((row >> 1) & 3)) * 8]);
        }
        __builtin_amdgcn_s_setprio(1);
#pragma unroll
        for (int m = 0; m < 2; ++m)
#pragma unroll
            for (int n = 0; n < 4; ++n)
                acc[m][n] = mfma16(af[m], bfr[n], acc[m][n]);
        __builtin_amdgcn_s_setprio(0);

        cur = (cur == 2) ? 0 : cur + 1;
        nxt = (nxt == 2) ? 0 : nxt + 1;
    }

#pragma unroll
    for (int m = 0; m < 2; ++m)
#pragma unroll
        for (int n = 0; n < 4; ++n)
#pragma unroll
            for (int ri = 0; ri < 4; ++ri)
                Cf[(size_t)(m0 + wr + m * 16 + g * 4 + ri) * N + n0 + wc + n * 16 + rl] =
                    acc[m][n][ri];
}

// ---------------------------------------------------------------
// Attention, 32x32 MFMA + in-register P (T12). NO LDS STAGING: K/V are
// L2/L3-resident (FETCH ~12MB), so each wave reads its fragments straight
// from global at iteration top (kf waits leave vf in flight under QK^T).
// Zero barriers in the k-loop. 4 waves = (q-half) x (k-parity); partial O's
// summed via a one-time 16KB-LDS reduce (no softmax -> plain add).
__global__ __launch_bounds__(256, 4) void k_attn(const bf* __restrict__ Qn,  // [B*H,S,64]
                                                 const bf* __restrict__ Kn,  // [B*H,S,64]
                                                 const bf* __restrict__ Vt,  // [B*H,64,S]
                                                 bf* __restrict__ Ctx) {     // [B*S, D]
    __shared__ float red[2][32][64];      // 16 KB

    const int idx = blockIdx.x;
    const int qt = 31 - (idx >> 5);       // 0..31, largest-first (LPT)
    const int by = idx & 31;              // b*H + h
    const int b = by >> 4, h = by & 15;
    const int tid = threadIdx.x;
    const int w = tid >> 6, lane = tid & 63;
    const int l31 = lane & 31, hl = lane >> 5;
    const int qh = w >> 1;                // q-half: rows qt*64+qh*32 ..+32
    const int kp = w & 1;                 // k-parity: subtiles kb = kp*32 + i*64
    const int qw = qt * 64 + qh * 32;
    const int qg = qw + l31;

    const bf* Qp = Qn + (size_t)by * SS * 64;
    const bf* Kp = Kn + (size_t)by * SS * 64;
    const bf* Vp = Vt + (size_t)by * 64 * SS;

    // hoisted Q (B-operand): col=q=l31, d = st*16 + hl*8 + 0..7
    bf16x8 aqs[4];
#pragma unroll
    for (int st = 0; st < 4; ++st)
        aqs[st] = __builtin_bit_cast(bf16x8,
            *(const int4*)(Qp + (size_t)(qw + l31) * 64 + st * 16 + hl * 8));

    f32x16 accd[2] = {};
    const int nsub = ((qw + 31 - kp * 32) >> 6) + 1;   // exact subtile count

    for (int i = 0; i < nsub; ++i) {
        const int kb = kp * 32 + i * 64;
        // ---- fragment loads straight from L2 (kf first; vf lands under QK^T)
        bf16x8 kf[4], vf[4];
#pragma unroll
        for (int st = 0; st < 4; ++st)
            kf[st] = __builtin_bit_cast(bf16x8,
                *(const int4*)(Kp + (size_t)(kb + l31) * 64 + st * 16 + hl * 8));
#pragma unroll
        for (int s = 0; s < 2; ++s)
#pragma unroll
            for (int dt = 0; dt < 2; ++dt)
                vf[s * 2 + dt] = __builtin_bit_cast(bf16x8,
                    *(const int4*)(Vp + (size_t)(dt * 32 + l31) * SS + kb + (s * 2 + hl) * 8));
        // ---- QK^T (swapped): D[row=k][col=q]
        f32x16 pc = {};
#pragma unroll
        for (int st = 0; st < 4; ++st)
            pc = mfma32(kf[st], aqs[st], pc);
        // ---- relu + causal (elementwise only near diagonal)
        const bool dg = (kb + 31 > qw);
        float pv[16];
#pragma unroll
        for (int m2 = 0; m2 < 16; ++m2) {
            float v = fmaxf(pc[m2], 0.0f);
            if (dg) {
                const int kg = kb + (m2 & 3) + 8 * (m2 >> 2) + 4 * hl;
                if (kg > qg) v = 0.0f;
            }
            pv[m2] = v;
        }
        // ---- pack to bf16 pairs + permlane swaps -> PV A-frags (no LDS)
        unsigned P[8];
#pragma unroll
        for (int m2 = 0; m2 < 8; ++m2) P[m2] = cvt_pk_bf16(pv[2 * m2], pv[2 * m2 + 1]);
        pl32swap(P[0], P[2]);
        pl32swap(P[1], P[3]);
        pl32swap(P[4], P[6]);
        pl32swap(P[5], P[7]);
        // ---- PV: D[row=q][col=d]
#pragma unroll
        for (int s = 0; s < 2; ++s) {
            uint4 pw = {P[4 * s + 0], P[4 * s + 1], P[4 * s + 2], P[4 * s + 3]};
            bf16x8 pa = __builtin_bit_cast(bf16x8, pw);
#pragma unroll
            for (int dt = 0; dt < 2; ++dt)
                accd[dt] = mfma32(pa, vf[s * 2 + dt], accd[dt]);
        }
    }

    // ---- cross-wave (k-parity) reduce via LDS, then kp==0 writes Ctx
    if (kp == 1) {
#pragma unroll
        for (int dt = 0; dt < 2; ++dt)
#pragma unroll
            for (int m2 = 0; m2 < 16; ++m2)
                red[qh][dt * 16 + m2][lane] = accd[dt][m2];
    }
    __syncthreads();
    if (kp == 0) {
#pragma unroll
        for (int dt = 0; dt < 2; ++dt)
#pragma unroll
            for (int m2 = 0; m2 < 16; ++m2) {
                const float v = accd[dt][m2] + red[qh][dt * 16 + m2][lane];
                const int q = qw + (m2 & 3) + 8 * (m2 >> 2) + 4 * hl;
                const int d = dt * 32 + l31;
                Ctx[(size_t)(b * SS + q) * DD + h * 64 + d] = __float2bfloat16(v);
            }
    }
}

// ---------------------------------------------------------------
extern "C" void kernel_launch(void* const* d_in, const int* in_sizes, int n_in,
                              void* d_out, int out_size, void* d_ws, size_t ws_size,
                              hipStream_t stream) {
    const float* X  = (const float*)d_in[0];
    const int* masks = (const int*)d_in[1];
    const float* Wq = (const float*)d_in[2];
    const float* Wk = (const float*)d_in[3];
    const float* Wv = (const float*)d_in[4];
    const float* Wo = (const float*)d_in[5];
    float* out = (float*)d_out;
    char* ws = (char*)d_ws;

    const size_t MB = 1024 * 1024;
    bf* Xb   = (bf*)(ws);              // 8 MB  [B*S, D]
    bf* Wqkv = (bf*)(ws + 8  * MB);    // 6 MB  [3072, 1024]
    bf* Wob  = (bf*)(ws + 14 * MB);    // 2 MB
    bf* Qn   = (bf*)(ws + 16 * MB);    // 8 MB  [B*H, S, 64]
    bf* Kn   = (bf*)(ws + 24 * MB);
    bf* Vt   = (bf*)(ws + 32 * MB);    // 8 MB  [B*H, 64, S]
    bf* Ctx  = (bf*)(ws + 40 * MB);    // 8 MB  [B*S, D]

    // converts (one launch)
    k_convert<<<8192, 256, 0, stream>>>(X, Wq, Wk, Wv, Wo, Xb, Wqkv, Wob);

    // fused QKV projection + norm/mask epilogue + V-transpose (768 blocks, 8 waves)
    k_gemm8<<<(ND3 / 128) * (MMR / 128), 512, 0, stream>>>(
        Xb, Wqkv, masks, Qn, Kn, Vt, ND3 / 128, DD);

    // attention (no-LDS-staging, barrier-free k-loop)
    k_attn<<<1024, 256, 0, stream>>>(Qn, Kn, Vt, Ctx);

    // output projection (64x128 tiles -> 512 blocks)
    k_gemm<<<(DD / 128) * (MMR / 64), 256, 0, stream>>>(
        Ctx, Wob, out, DD / 128, DD, DD);
}

// Round 8
// 122.124 us; speedup vs baseline: 1.1536x; 1.1536x over previous
//
#include <hip/hip_runtime.h>
#include <hip/hip_bf16.h>

// Problem constants
#define BB 2
#define SS 2048
#define DD 1024
#define HH 16
#define MMR (BB*SS)   // 4096 rows
#define ND3 3072      // fused QKV width

typedef __hip_bfloat16 bf;
typedef __bf16 bf16x8 __attribute__((ext_vector_type(8)));
typedef float f32x4 __attribute__((ext_vector_type(4)));
typedef float f32x16 __attribute__((ext_vector_type(16)));

#define VMCNT(n) asm volatile("s_waitcnt vmcnt(" #n ")" ::: "memory")

__device__ __forceinline__ f32x4 mfma16(bf16x8 a, bf16x8 b, f32x4 c) {
    return __builtin_amdgcn_mfma_f32_16x16x32_bf16(a, b, c, 0, 0, 0);
}
__device__ __forceinline__ f32x16 mfma32(bf16x8 a, bf16x8 b, f32x16 c) {
    return __builtin_amdgcn_mfma_f32_32x32x16_bf16(a, b, c, 0, 0, 0);
}
__device__ __forceinline__ unsigned cvt_pk_bf16(float lo, float hi) {
    unsigned r;
    asm("v_cvt_pk_bf16_f32 %0, %1, %2" : "=v"(r) : "v"(lo), "v"(hi));
    return r;
}
// after: a = {a.lo31, b.lo31}, b = {a.hi31, b.hi31}
__device__ __forceinline__ void pl32swap(unsigned& a, unsigned& b) {
    asm("v_permlane32_swap_b32 %0, %1" : "+v"(a), "+v"(b));
}
// async global->LDS, 16B/lane; LDS dest = wave-uniform base + lane*16
__device__ __forceinline__ void glds16(const bf* g, bf* l) {
    __builtin_amdgcn_global_load_lds(
        (const __attribute__((address_space(1))) void*)g,
        (__attribute__((address_space(3))) void*)l,
        16, 0, 0);
}

// ---------------------------------------------------------------
// All f32->bf16 converts in ONE launch. blocks 0..4095: X (4M elems);
// blocks 4096..8191: Wq,Wk,Wv (into Wqkv) and Wo (into Wob), 1M each.
__global__ __launch_bounds__(256) void k_convert(const float* __restrict__ X,
                                                 const float* __restrict__ Wq,
                                                 const float* __restrict__ Wk,
                                                 const float* __restrict__ Wv,
                                                 const float* __restrict__ Wo,
                                                 bf* __restrict__ Xb,
                                                 bf* __restrict__ Wqkv,
                                                 bf* __restrict__ Wob) {
    const int bid = blockIdx.x;
    const float* src;
    bf* dst;
    int off;
    if (bid < 4096) {
        src = X; dst = Xb; off = bid;
    } else {
        const int r = (bid - 4096) >> 10;
        src = (r == 0) ? Wq : (r == 1) ? Wk : (r == 2) ? Wv : Wo;
        dst = (r < 3) ? (Wqkv + (size_t)r * 1048576) : Wob;
        off = (bid - 4096) & 1023;
    }
    const int j = (off * 256 + threadIdx.x) * 4;
    float4 v = *(const float4*)(src + j);
    bf tmp[4];
    tmp[0] = __float2bfloat16(v.x);
    tmp[1] = __float2bfloat16(v.y);
    tmp[2] = __float2bfloat16(v.z);
    tmp[3] = __float2bfloat16(v.w);
    *(uint2*)(dst + j) = *(const uint2*)tmp;
}

// ---------------------------------------------------------------
// QKV GEMM: 128x128 tile, BK=32, 8 waves (512 thr), wave = 32x64 quadrant.
// 3-buffer LDS pipeline, counted vmcnt, raw s_barrier, seg-XOR LDS swizzle.
// Fused epilogue: cols<2048 -> per-head L2-norm * mask -> Qn/Kn [B*H,S,64];
// cols>=2048 -> transposed bf16 write to Vt [B*H,64,S].
__global__ __launch_bounds__(512, 6) void k_gemm8(const bf* __restrict__ A,
                                                  const bf* __restrict__ Bt,
                                                  const int* __restrict__ masks,
                                                  bf* __restrict__ Qn,
                                                  bf* __restrict__ Kn,
                                                  bf* __restrict__ Vt,
                                                  int nx, int K) {
    __shared__ __align__(16) bf Asm[3][128 * 32];
    __shared__ __align__(16) bf Bsm[3][128 * 32];
    const int tid = threadIdx.x;
    const int w = tid >> 6, lane = tid & 63, g = lane >> 4, rl = lane & 15;
    const int cpx = gridDim.x >> 3;
    const int swz = (blockIdx.x & 7) * cpx + (blockIdx.x >> 3);
    const int m0 = (swz / nx) * 128, n0 = (swz % nx) * 128;
    const int wr = (w >> 1) * 32, wc = (w & 1) * 64;
    const int lrow = lane >> 2, lseg = lane & 3;
    const int xseg = lseg ^ ((lrow >> 1) & 3);   // pre-swizzled source seg

    f32x4 acc[2][4] = {};
    const bf* Ap = A + (size_t)m0 * K;
    const bf* Bp = Bt + (size_t)n0 * K;

    auto stage = [&](int bi, int k0) {
        glds16(Ap + (size_t)(w * 16 + lrow) * K + k0 + xseg * 8, &Asm[bi][w * 512]);
        glds16(Bp + (size_t)(w * 16 + lrow) * K + k0 + xseg * 8, &Bsm[bi][w * 512]);
    };

    const int T = K >> 5;
    stage(0, 0);
    stage(1, 32);
    int cur = 0, nxt = 2;
    for (int t = 0; t < T; ++t) {
        __builtin_amdgcn_sched_barrier(0);
        if (t < T - 1) { VMCNT(2); } else { VMCNT(0); }
        __builtin_amdgcn_s_barrier();     // staged loads stay in flight
        __builtin_amdgcn_sched_barrier(0);
        if (t + 2 < T) stage(nxt, (t + 2) * 32);

        const bf* Ab = Asm[cur];
        const bf* Bb = Bsm[cur];
        bf16x8 af[2], bfr[4];
#pragma unroll
        for (int m = 0; m < 2; ++m) {
            const int row = wr + m * 16 + rl;
            af[m] = __builtin_bit_cast(bf16x8,
                *(const int4*)&Ab[row * 32 + (g ^ ((row >> 1) & 3)) * 8]);
        }
#pragma unroll
        for (int n = 0; n < 4; ++n) {
            const int row = wc + n * 16 + rl;
            bfr[n] = __builtin_bit_cast(bf16x8,
                *(const int4*)&Bb[row * 32 + (g ^ ((row >> 1) & 3)) * 8]);
        }
        __builtin_amdgcn_s_setprio(1);
#pragma unroll
        for (int m = 0; m < 2; ++m)
#pragma unroll
            for (int n = 0; n < 4; ++n)
                acc[m][n] = mfma16(af[m], bfr[n], acc[m][n]);
        __builtin_amdgcn_s_setprio(0);

        cur = (cur == 2) ? 0 : cur + 1;
        nxt = (nxt == 2) ? 0 : nxt + 1;
    }

    const int ncol0 = n0 + wc;   // wave's 64-col base == one head slice
    if (ncol0 < 2048) {
        bf* dst = (ncol0 < 1024) ? Qn : Kn;
        const int h2 = (ncol0 >> 6) & 15;
#pragma unroll
        for (int m = 0; m < 2; ++m) {
#pragma unroll
            for (int ri = 0; ri < 4; ++ri) {
                const int row = m0 + wr + m * 16 + g * 4 + ri;   // b*S+s
                float ss = 0.f;
#pragma unroll
                for (int n = 0; n < 4; ++n) ss += acc[m][n][ri] * acc[m][n][ri];
#pragma unroll
                for (int d = 1; d < 16; d <<= 1) ss += __shfl_xor(ss, d, 64);
                const float sc = rsqrtf(ss) * (masks[row] ? 1.0f : 0.0f);
                const int b = row >> 11, s = row & 2047;
                const size_t base = ((size_t)(b * HH + h2) * SS + s) * 64;
#pragma unroll
                for (int n = 0; n < 4; ++n)
                    dst[base + n * 16 + rl] = __float2bfloat16(acc[m][n][ri] * sc);
            }
        }
    } else {
        // fused V transpose: Vt[(b*H+h)*64 + d][s], packed 4-bf16 writes
        const int h2 = (ncol0 - 2048) >> 6;
        const int b = (m0 + wr) >> 11;
        const int sb = ((m0 + wr) & 2047) + g * 4;
#pragma unroll
        for (int m = 0; m < 2; ++m)
#pragma unroll
            for (int n = 0; n < 4; ++n) {
                const int d = n * 16 + rl;
                bf t4[4];
#pragma unroll
                for (int ri = 0; ri < 4; ++ri) t4[ri] = __float2bfloat16(acc[m][n][ri]);
                *(uint2*)&Vt[((size_t)(b * HH + h2) * 64 + d) * SS + sb + m * 16] =
                    *(uint2*)t4;
            }
    }
}

// ---------------------------------------------------------------
// Out-proj GEMM: 64x128 tile, BK=32, 4 waves, 3-buffer counted-vmcnt pipeline.
__global__ __launch_bounds__(256) void k_gemm(const bf* __restrict__ A,
                                              const bf* __restrict__ Bt,
                                              float* __restrict__ Cf,
                                              int nx, int N, int K) {
    constexpr int BM = 64, BN = 128;
    __shared__ __align__(16) bf Asm[3][BM * 32];
    __shared__ __align__(16) bf Bsm[3][BN * 32];
    const int tid = threadIdx.x;
    const int w = tid >> 6, lane = tid & 63, g = lane >> 4, rl = lane & 15;
    const int cpx = gridDim.x >> 3;
    const int swz = (blockIdx.x & 7) * cpx + (blockIdx.x >> 3);
    const int m0 = (swz / nx) * BM, n0 = (swz % nx) * BN;
    const int wr = (w >> 1) * 32, wc = (w & 1) * 64;
    const int lrow = lane >> 2, lseg = lane & 3;
    const int xseg = lseg ^ ((lrow >> 1) & 3);

    f32x4 acc[2][4] = {};
    const bf* Ap = A + (size_t)m0 * K;
    const bf* Bp = Bt + (size_t)n0 * K;

    auto stage = [&](int bi, int k0) {
        glds16(Ap + (size_t)(w * 16 + lrow) * K + k0 + xseg * 8, &Asm[bi][w * 512]);
#pragma unroll
        for (int u = 0; u < 2; ++u)
            glds16(Bp + (size_t)(u * 64 + w * 16 + lrow) * K + k0 + xseg * 8,
                   &Bsm[bi][(u * 64 + w * 16) * 32]);
    };

    const int T = K >> 5;
    stage(0, 0);
    stage(1, 32);
    int cur = 0, nxt = 2;
    for (int t = 0; t < T; ++t) {
        __builtin_amdgcn_sched_barrier(0);
        if (t < T - 1) { VMCNT(3); } else { VMCNT(0); }
        __builtin_amdgcn_s_barrier();
        __builtin_amdgcn_sched_barrier(0);
        if (t + 2 < T) stage(nxt, (t + 2) * 32);

        const bf* Ab = Asm[cur];
        const bf* Bb = Bsm[cur];
        bf16x8 af[2], bfr[4];
#pragma unroll
        for (int m = 0; m < 2; ++m) {
            const int row = wr + m * 16 + rl;
            af[m] = __builtin_bit_cast(bf16x8,
                *(const int4*)&Ab[row * 32 + (g ^ ((row >> 1) & 3)) * 8]);
        }
#pragma unroll
        for (int n = 0; n < 4; ++n) {
            const int row = wc + n * 16 + rl;
            bfr[n] = __builtin_bit_cast(bf16x8,
                *(const int4*)&Bb[row * 32 + (g ^ ((row >> 1) & 3)) * 8]);
        }
        __builtin_amdgcn_s_setprio(1);
#pragma unroll
        for (int m = 0; m < 2; ++m)
#pragma unroll
            for (int n = 0; n < 4; ++n)
                acc[m][n] = mfma16(af[m], bfr[n], acc[m][n]);
        __builtin_amdgcn_s_setprio(0);

        cur = (cur == 2) ? 0 : cur + 1;
        nxt = (nxt == 2) ? 0 : nxt + 1;
    }

#pragma unroll
    for (int m = 0; m < 2; ++m)
#pragma unroll
        for (int n = 0; n < 4; ++n)
#pragma unroll
            for (int ri = 0; ri < 4; ++ri)
                Cf[(size_t)(m0 + wr + m * 16 + g * 4 + ri) * N + n0 + wc + n * 16 + rl] =
                    acc[m][n][ri];
}

// ---------------------------------------------------------------
// Attention: q-tile 128, 512 blocks (LPT), 4 waves = (q-half qh: 64q) x
// (k-parity kp). Each wave owns 64 q rows (2 q-groups of 32) -> every LDS
// K/V fragment read feeds TWO mfma32 (2x operand reuse vs r6).
// 3-buffer K/V pipeline, counted vmcnt before raw s_barrier (r6-proven).
// In-register P via cvt_pk + permlane32_swap. k-parity partials summed via
// one-time 32KB LDS reduce over the staging buffer (no softmax -> plain add).
__global__ __launch_bounds__(256, 2) void k_attn(const bf* __restrict__ Qn,  // [B*H,S,64]
                                                 const bf* __restrict__ Kn,  // [B*H,S,64]
                                                 const bf* __restrict__ Vt,  // [B*H,64,S]
                                                 bf* __restrict__ Ctx) {     // [B*S, D]
    __shared__ __align__(16) bf smem[6 * 4096];   // 48KB: K[3][4096] | V[3][4096]

    const int idx = blockIdx.x;
    const int qt = 15 - (idx >> 5);       // 0..15 (128-row q tiles), largest-first
    const int by = idx & 31;              // b*H + h
    const int b = by >> 4, h = by & 15;
    const int tid = threadIdx.x;
    const int w = tid >> 6, lane = tid & 63;
    const int l31 = lane & 31, hl = lane >> 5;
    const int qh = w >> 1;                // q-half: 64 rows
    const int kp = w & 1;                 // k-parity: subtile kb = t*64 + kp*32
    const int qw = qt * 128 + qh * 64;    // wave's first q row (64 rows)

    const bf* Qp = Qn + (size_t)by * SS * 64;
    const bf* Kp = Kn + (size_t)by * SS * 64;
    const bf* Vp = Vt + (size_t)by * 64 * SS;

    // hoisted Q (B-operand), 2 q-groups x 4 K-steps
    bf16x8 aqs0[4], aqs1[4];
#pragma unroll
    for (int st = 0; st < 4; ++st) {
        aqs0[st] = __builtin_bit_cast(bf16x8,
            *(const int4*)(Qp + (size_t)(qw + l31) * 64 + st * 16 + hl * 8));
        aqs1[st] = __builtin_bit_cast(bf16x8,
            *(const int4*)(Qp + (size_t)(qw + 32 + l31) * 64 + st * 16 + hl * 8));
    }

    // staging: chunk = 8 rows x 128B; pre-swizzled source slot. 16 chunks
    // (8 K + 8 V) over 4 waves -> 4 glds16/thread/stage.
    const int srow = lane >> 3;
    const int sblk = (lane & 7) ^ srow;

    auto stage = [&](int buf, int k0) {
#pragma unroll
        for (int u = 0; u < 4; ++u) {
            const int c = w * 4 + u;              // 0..15
            if (c < 8) {                          // K chunk c
                const int row = c * 8 + srow;
                glds16(Kp + (size_t)(k0 + row) * 64 + sblk * 8,
                       &smem[buf * 4096 + c * 512]);
            } else {                              // V chunk c-8
                const int row = (c - 8) * 8 + srow;
                glds16(Vp + (size_t)row * SS + k0 + sblk * 8,
                       &smem[(3 + buf) * 4096 + (c - 8) * 512]);
            }
        }
    };

    f32x16 accd0[2] = {}, accd1[2] = {};
    const int tmax = 2 * qt + 1;          // k-tiles 0..tmax (64 keys each)

    stage(0, 0);
    stage(1, 64);
    int cur = 0, nxt = 2;
    for (int t = 0; t <= tmax; ++t) {
        __builtin_amdgcn_sched_barrier(0);
        if (t < tmax) { VMCNT(4); } else { VMCNT(0); }
        __builtin_amdgcn_s_barrier();     // all waves' tile-t chunks landed
        __builtin_amdgcn_sched_barrier(0);
        if (t + 2 <= tmax) stage(nxt, (t + 2) * 64);

        const int kb = t * 64 + kp * 32;
        if (kb <= qw + 63) {
            const bf* Ks = &smem[cur * 4096];
            const bf* Vs = &smem[(3 + cur) * 4096];
            const bool need0 = (kb <= qw + 31);   // q-group 0 relevance
            // ---- QK^T (swapped): each ak read feeds both q-groups
            f32x16 pc0 = {}, pc1 = {};
            const int r = kp * 32 + l31;
            __builtin_amdgcn_s_setprio(1);
#pragma unroll
            for (int st = 0; st < 4; ++st) {
                bf16x8 ak = __builtin_bit_cast(bf16x8,
                    *(const int4*)&Ks[r * 64 + (((2 * st + hl) ^ (r & 7)) << 3)]);
                if (need0) pc0 = mfma32(ak, aqs0[st], pc0);
                pc1 = mfma32(ak, aqs1[st], pc1);
            }
            __builtin_amdgcn_s_setprio(0);
            // ---- relu + causal + pack -> PV A-frags (per q-group)
            bf16x8 pa0[2], pa1[2];
            if (need0) {
                const bool dg = (kb + 31 > qw);
                float pv[16];
#pragma unroll
                for (int m2 = 0; m2 < 16; ++m2) {
                    float v = fmaxf(pc0[m2], 0.0f);
                    if (dg) {
                        const int kg = kb + (m2 & 3) + 8 * (m2 >> 2) + 4 * hl;
                        if (kg > qw + l31) v = 0.0f;
                    }
                    pv[m2] = v;
                }
                unsigned P[8];
#pragma unroll
                for (int m2 = 0; m2 < 8; ++m2) P[m2] = cvt_pk_bf16(pv[2 * m2], pv[2 * m2 + 1]);
                pl32swap(P[0], P[2]); pl32swap(P[1], P[3]);
                pl32swap(P[4], P[6]); pl32swap(P[5], P[7]);
                uint4 w0 = {P[0], P[1], P[2], P[3]}, w1 = {P[4], P[5], P[6], P[7]};
                pa0[0] = __builtin_bit_cast(bf16x8, w0);
                pa0[1] = __builtin_bit_cast(bf16x8, w1);
            }
            {
                const bool dg = (kb + 31 > qw + 32);
                float pv[16];
#pragma unroll
                for (int m2 = 0; m2 < 16; ++m2) {
                    float v = fmaxf(pc1[m2], 0.0f);
                    if (dg) {
                        const int kg = kb + (m2 & 3) + 8 * (m2 >> 2) + 4 * hl;
                        if (kg > qw + 32 + l31) v = 0.0f;
                    }
                    pv[m2] = v;
                }
                unsigned P[8];
#pragma unroll
                for (int m2 = 0; m2 < 8; ++m2) P[m2] = cvt_pk_bf16(pv[2 * m2], pv[2 * m2 + 1]);
                pl32swap(P[0], P[2]); pl32swap(P[1], P[3]);
                pl32swap(P[4], P[6]); pl32swap(P[5], P[7]);
                uint4 w0 = {P[0], P[1], P[2], P[3]}, w1 = {P[4], P[5], P[6], P[7]};
                pa1[0] = __builtin_bit_cast(bf16x8, w0);
                pa1[1] = __builtin_bit_cast(bf16x8, w1);
            }
            // ---- PV: each bv read feeds both q-groups
            __builtin_amdgcn_s_setprio(1);
#pragma unroll
            for (int s = 0; s < 2; ++s)
#pragma unroll
                for (int dt = 0; dt < 2; ++dt) {
                    const int d = dt * 32 + l31;
                    const int slot = kp * 4 + s * 2 + hl;
                    bf16x8 bv = __builtin_bit_cast(bf16x8,
                        *(const int4*)&Vs[d * 64 + ((slot ^ (d & 7)) << 3)]);
                    if (need0) accd0[dt] = mfma32(pa0[s], bv, accd0[dt]);
                    accd1[dt] = mfma32(pa1[s], bv, accd1[dt]);
                }
            __builtin_amdgcn_s_setprio(0);
        }

        cur = (cur == 2) ? 0 : cur + 1;
        nxt = (nxt == 2) ? 0 : nxt + 1;
    }

    // ---- cross-wave (k-parity) reduce: kp==1 partials via 32KB LDS
    __syncthreads();                      // all tile reads done before reuse
    float* red = (float*)smem;            // [128 q][64 d] f32 = 32KB
    if (kp == 1) {
#pragma unroll
        for (int dt = 0; dt < 2; ++dt)
#pragma unroll
            for (int m2 = 0; m2 < 16; ++m2) {
                const int crow = (m2 & 3) + 8 * (m2 >> 2) + 4 * hl;
                red[(qh * 64 + crow) * 64 + dt * 32 + l31] = accd0[dt][m2];
                red[(qh * 64 + 32 + crow) * 64 + dt * 32 + l31] = accd1[dt][m2];
            }
    }
    __syncthreads();
    if (kp == 0) {
#pragma unroll
        for (int dt = 0; dt < 2; ++dt)
#pragma unroll
            for (int m2 = 0; m2 < 16; ++m2) {
                const int crow = (m2 & 3) + 8 * (m2 >> 2) + 4 * hl;
                const int d = dt * 32 + l31;
                const float v0 = accd0[dt][m2] + red[(qh * 64 + crow) * 64 + d];
                const float v1 = accd1[dt][m2] + red[(qh * 64 + 32 + crow) * 64 + d];
                const int q0 = qt * 128 + qh * 64 + crow;
                Ctx[(size_t)(b * SS + q0) * DD + h * 64 + d] = __float2bfloat16(v0);
                Ctx[(size_t)(b * SS + q0 + 32) * DD + h * 64 + d] = __float2bfloat16(v1);
            }
    }
}

// ---------------------------------------------------------------
extern "C" void kernel_launch(void* const* d_in, const int* in_sizes, int n_in,
                              void* d_out, int out_size, void* d_ws, size_t ws_size,
                              hipStream_t stream) {
    const float* X  = (const float*)d_in[0];
    const int* masks = (const int*)d_in[1];
    const float* Wq = (const float*)d_in[2];
    const float* Wk = (const float*)d_in[3];
    const float* Wv = (const float*)d_in[4];
    const float* Wo = (const float*)d_in[5];
    float* out = (float*)d_out;
    char* ws = (char*)d_ws;

    const size_t MB = 1024 * 1024;
    bf* Xb   = (bf*)(ws);              // 8 MB  [B*S, D]
    bf* Wqkv = (bf*)(ws + 8  * MB);    // 6 MB  [3072, 1024]
    bf* Wob  = (bf*)(ws + 14 * MB);    // 2 MB
    bf* Qn   = (bf*)(ws + 16 * MB);    // 8 MB  [B*H, S, 64]
    bf* Kn   = (bf*)(ws + 24 * MB);
    bf* Vt   = (bf*)(ws + 32 * MB);    // 8 MB  [B*H, 64, S]
    bf* Ctx  = (bf*)(ws + 40 * MB);    // 8 MB  [B*S, D]

    // converts (one launch)
    k_convert<<<8192, 256, 0, stream>>>(X, Wq, Wk, Wv, Wo, Xb, Wqkv, Wob);

    // fused QKV projection + norm/mask epilogue + V-transpose (768 blocks, 8 waves)
    k_gemm8<<<(ND3 / 128) * (MMR / 128), 512, 0, stream>>>(
        Xb, Wqkv, masks, Qn, Kn, Vt, ND3 / 128, DD);

    // attention (q-tile 128, 2x LDS operand reuse)
    k_attn<<<512, 256, 0, stream>>>(Qn, Kn, Vt, Ctx);

    // output projection (64x128 tiles -> 512 blocks)
    k_gemm<<<(DD / 128) * (MMR / 64), 256, 0, stream>>>(
        Ctx, Wob, out, DD / 128, DD, DD);
}

// Round 9
// 104.138 us; speedup vs baseline: 1.3528x; 1.1727x over previous
//
#include <hip/hip_runtime.h>
#include <hip/hip_bf16.h>

// Problem constants
#define BB 2
#define SS 2048
#define DD 1024
#define HH 16
#define MMR (BB*SS)   // 4096 rows
#define ND3 3072      // fused QKV width

typedef __hip_bfloat16 bf;
typedef __bf16 bf16x8 __attribute__((ext_vector_type(8)));
typedef float f32x4 __attribute__((ext_vector_type(4)));
typedef float f32x16 __attribute__((ext_vector_type(16)));

#define VMCNT(n) asm volatile("s_waitcnt vmcnt(" #n ")" ::: "memory")

__device__ __forceinline__ f32x4 mfma16(bf16x8 a, bf16x8 b, f32x4 c) {
    return __builtin_amdgcn_mfma_f32_16x16x32_bf16(a, b, c, 0, 0, 0);
}
__device__ __forceinline__ f32x16 mfma32(bf16x8 a, bf16x8 b, f32x16 c) {
    return __builtin_amdgcn_mfma_f32_32x32x16_bf16(a, b, c, 0, 0, 0);
}
__device__ __forceinline__ unsigned cvt_pk_bf16(float lo, float hi) {
    unsigned r;
    asm("v_cvt_pk_bf16_f32 %0, %1, %2" : "=v"(r) : "v"(lo), "v"(hi));
    return r;
}
// after: a = {a.lo31, b.lo31}, b = {a.hi31, b.hi31}
__device__ __forceinline__ void pl32swap(unsigned& a, unsigned& b) {
    asm("v_permlane32_swap_b32 %0, %1" : "+v"(a), "+v"(b));
}
// async global->LDS, 16B/lane; LDS dest = wave-uniform base + lane*16
__device__ __forceinline__ void glds16(const bf* g, bf* l) {
    __builtin_amdgcn_global_load_lds(
        (const __attribute__((address_space(1))) void*)g,
        (__attribute__((address_space(3))) void*)l,
        16, 0, 0);
}

// ---------------------------------------------------------------
// All f32->bf16 converts in ONE launch. blocks 0..4095: X (4M elems);
// blocks 4096..8191: Wq,Wk,Wv (into Wqkv) and Wo (into Wob), 1M each.
__global__ __launch_bounds__(256) void k_convert(const float* __restrict__ X,
                                                 const float* __restrict__ Wq,
                                                 const float* __restrict__ Wk,
                                                 const float* __restrict__ Wv,
                                                 const float* __restrict__ Wo,
                                                 bf* __restrict__ Xb,
                                                 bf* __restrict__ Wqkv,
                                                 bf* __restrict__ Wob) {
    const int bid = blockIdx.x;
    const float* src;
    bf* dst;
    int off;
    if (bid < 4096) {
        src = X; dst = Xb; off = bid;
    } else {
        const int r = (bid - 4096) >> 10;
        src = (r == 0) ? Wq : (r == 1) ? Wk : (r == 2) ? Wv : Wo;
        dst = (r < 3) ? (Wqkv + (size_t)r * 1048576) : Wob;
        off = (bid - 4096) & 1023;
    }
    const int j = (off * 256 + threadIdx.x) * 4;
    float4 v = *(const float4*)(src + j);
    bf tmp[4];
    tmp[0] = __float2bfloat16(v.x);
    tmp[1] = __float2bfloat16(v.y);
    tmp[2] = __float2bfloat16(v.z);
    tmp[3] = __float2bfloat16(v.w);
    *(uint2*)(dst + j) = *(const uint2*)tmp;
}

// ---------------------------------------------------------------
// QKV GEMM: 128x256 tile, BK=32, 8 waves (512 thr), wave = 64x64 (4x4 acc,
// 8 ds_read_b128 per 16 MFMA). 2-buffer LDS (48KB -> up to 3 blocks/CU),
// stage->compute->syncthreads loop. seg-XOR LDS swizzle (0-conflict,
// r6-verified). Grid 384 blocks (%8==0, XCD swizzle).
// Fused epilogue (wave's 64 cols == one head slice): cols<2048 -> per-head
// L2-norm * mask -> Qn/Kn [B*H,S,64]; cols>=2048 -> transposed Vt [B*H,64,S].
__global__ __launch_bounds__(512, 2) void k_gemmq(const bf* __restrict__ A,
                                                  const bf* __restrict__ Bt,
                                                  const int* __restrict__ masks,
                                                  bf* __restrict__ Qn,
                                                  bf* __restrict__ Kn,
                                                  bf* __restrict__ Vt,
                                                  int nx, int K) {
    __shared__ __align__(16) bf Asm[2][128 * 32];   // 16KB
    __shared__ __align__(16) bf Bsm[2][256 * 32];   // 32KB
    const int tid = threadIdx.x;
    const int w = tid >> 6, lane = tid & 63, g = lane >> 4, rl = lane & 15;
    const int cpx = gridDim.x >> 3;
    const int swz = (blockIdx.x & 7) * cpx + (blockIdx.x >> 3);
    const int m0 = (swz / nx) * 128, n0 = (swz % nx) * 256;
    const int wr = (w >> 2) * 64;        // 0 or 64
    const int wc = (w & 3) * 64;         // 0..192
    const int lrow = lane >> 2, lseg = lane & 3;
    const int xseg = lseg ^ ((lrow >> 1) & 3);   // pre-swizzled source seg

    f32x4 acc[4][4] = {};
    const bf* Ap = A + (size_t)m0 * K;
    const bf* Bp = Bt + (size_t)n0 * K;

    auto stage = [&](int bi, int k0) {
        // A: 128 rows = 8 chunks of 16; wave w owns chunk w
        glds16(Ap + (size_t)(w * 16 + lrow) * K + k0 + xseg * 8, &Asm[bi][w * 512]);
        // B: 256 rows = 16 chunks; wave w owns chunks 2w, 2w+1
#pragma unroll
        for (int u = 0; u < 2; ++u)
            glds16(Bp + (size_t)(w * 32 + u * 16 + lrow) * K + k0 + xseg * 8,
                   &Bsm[bi][(w * 32 + u * 16) * 32]);
    };

    const int T = K >> 5;
    stage(0, 0);
    __syncthreads();
    int cur = 0;
    for (int t = 0; t < T; ++t) {
        if (t + 1 < T) stage(cur ^ 1, (t + 1) * 32);   // loads fly under compute

        const bf* Ab = Asm[cur];
        const bf* Bb = Bsm[cur];
        bf16x8 af[4], bfr[4];
#pragma unroll
        for (int m = 0; m < 4; ++m) {
            const int row = wr + m * 16 + rl;
            af[m] = __builtin_bit_cast(bf16x8,
                *(const int4*)&Ab[row * 32 + (g ^ ((row >> 1) & 3)) * 8]);
        }
#pragma unroll
        for (int n = 0; n < 4; ++n) {
            const int row = wc + n * 16 + rl;
            bfr[n] = __builtin_bit_cast(bf16x8,
                *(const int4*)&Bb[row * 32 + (g ^ ((row >> 1) & 3)) * 8]);
        }
#pragma unroll
        for (int m = 0; m < 4; ++m)
#pragma unroll
            for (int n = 0; n < 4; ++n)
                acc[m][n] = mfma16(af[m], bfr[n], acc[m][n]);

        __syncthreads();                 // drains prefetch, protects buffers
        cur ^= 1;
    }

    const int ncol0 = n0 + wc;   // wave's 64-col base == one head slice
    if (ncol0 < 2048) {
        bf* dst = (ncol0 < 1024) ? Qn : Kn;
        const int h2 = (ncol0 >> 6) & 15;
#pragma unroll
        for (int m = 0; m < 4; ++m) {
#pragma unroll
            for (int ri = 0; ri < 4; ++ri) {
                const int row = m0 + wr + m * 16 + g * 4 + ri;   // b*S+s
                float ss = 0.f;
#pragma unroll
                for (int n = 0; n < 4; ++n) ss += acc[m][n][ri] * acc[m][n][ri];
#pragma unroll
                for (int d = 1; d < 16; d <<= 1) ss += __shfl_xor(ss, d, 64);
                const float sc = rsqrtf(ss) * (masks[row] ? 1.0f : 0.0f);
                const int b = row >> 11, s = row & 2047;
                const size_t base = ((size_t)(b * HH + h2) * SS + s) * 64;
#pragma unroll
                for (int n = 0; n < 4; ++n)
                    dst[base + n * 16 + rl] = __float2bfloat16(acc[m][n][ri] * sc);
            }
        }
    } else {
        // fused V transpose: Vt[(b*H+h)*64 + d][s], packed 4-bf16 writes
        const int h2 = (ncol0 - 2048) >> 6;
        const int b = (m0 + wr) >> 11;
        const int sb = ((m0 + wr) & 2047) + g * 4;
#pragma unroll
        for (int m = 0; m < 4; ++m)
#pragma unroll
            for (int n = 0; n < 4; ++n) {
                const int d = n * 16 + rl;
                bf t4[4];
#pragma unroll
                for (int ri = 0; ri < 4; ++ri) t4[ri] = __float2bfloat16(acc[m][n][ri]);
                *(uint2*)&Vt[((size_t)(b * HH + h2) * 64 + d) * SS + sb + m * 16] =
                    *(uint2*)t4;
            }
    }
}

// ---------------------------------------------------------------
// Out-proj GEMM: 64x128 tile, BK=32, 4 waves, 3-buffer counted-vmcnt pipeline.
__global__ __launch_bounds__(256) void k_gemm(const bf* __restrict__ A,
                                              const bf* __restrict__ Bt,
                                              float* __restrict__ Cf,
                                              int nx, int N, int K) {
    constexpr int BM = 64, BN = 128;
    __shared__ __align__(16) bf Asm[3][BM * 32];
    __shared__ __align__(16) bf Bsm[3][BN * 32];
    const int tid = threadIdx.x;
    const int w = tid >> 6, lane = tid & 63, g = lane >> 4, rl = lane & 15;
    const int cpx = gridDim.x >> 3;
    const int swz = (blockIdx.x & 7) * cpx + (blockIdx.x >> 3);
    const int m0 = (swz / nx) * BM, n0 = (swz % nx) * BN;
    const int wr = (w >> 1) * 32, wc = (w & 1) * 64;
    const int lrow = lane >> 2, lseg = lane & 3;
    const int xseg = lseg ^ ((lrow >> 1) & 3);

    f32x4 acc[2][4] = {};
    const bf* Ap = A + (size_t)m0 * K;
    const bf* Bp = Bt + (size_t)n0 * K;

    auto stage = [&](int bi, int k0) {
        glds16(Ap + (size_t)(w * 16 + lrow) * K + k0 + xseg * 8, &Asm[bi][w * 512]);
#pragma unroll
        for (int u = 0; u < 2; ++u)
            glds16(Bp + (size_t)(u * 64 + w * 16 + lrow) * K + k0 + xseg * 8,
                   &Bsm[bi][(u * 64 + w * 16) * 32]);
    };

    const int T = K >> 5;
    stage(0, 0);
    stage(1, 32);
    int cur = 0, nxt = 2;
    for (int t = 0; t < T; ++t) {
        __builtin_amdgcn_sched_barrier(0);
        if (t < T - 1) { VMCNT(3); } else { VMCNT(0); }
        __builtin_amdgcn_s_barrier();
        __builtin_amdgcn_sched_barrier(0);
        if (t + 2 < T) stage(nxt, (t + 2) * 32);

        const bf* Ab = Asm[cur];
        const bf* Bb = Bsm[cur];
        bf16x8 af[2], bfr[4];
#pragma unroll
        for (int m = 0; m < 2; ++m) {
            const int row = wr + m * 16 + rl;
            af[m] = __builtin_bit_cast(bf16x8,
                *(const int4*)&Ab[row * 32 + (g ^ ((row >> 1) & 3)) * 8]);
        }
#pragma unroll
        for (int n = 0; n < 4; ++n) {
            const int row = wc + n * 16 + rl;
            bfr[n] = __builtin_bit_cast(bf16x8,
                *(const int4*)&Bb[row * 32 + (g ^ ((row >> 1) & 3)) * 8]);
        }
        __builtin_amdgcn_s_setprio(1);
#pragma unroll
        for (int m = 0; m < 2; ++m)
#pragma unroll
            for (int n = 0; n < 4; ++n)
                acc[m][n] = mfma16(af[m], bfr[n], acc[m][n]);
        __builtin_amdgcn_s_setprio(0);

        cur = (cur == 2) ? 0 : cur + 1;
        nxt = (nxt == 2) ? 0 : nxt + 1;
    }

#pragma unroll
    for (int m = 0; m < 2; ++m)
#pragma unroll
        for (int n = 0; n < 4; ++n)
#pragma unroll
            for (int ri = 0; ri < 4; ++ri)
                Cf[(size_t)(m0 + wr + m * 16 + g * 4 + ri) * N + n0 + wc + n * 16 + rl] =
                    acc[m][n][ri];
}

// ---------------------------------------------------------------
// Attention (r4-proven structure, ~28us): 32x32 MFMA + in-register P (T12),
// q-tile 64, 1024 blocks (LPT). 4 waves = (q-half qh) x (k-parity kp).
// 2-buffer K/V staged via glds16 (XOR-swizzled source), single __syncthreads
// per tile (stage next -> compute current -> sync). Partial O's summed via
// one-time LDS reduce (no softmax -> plain add).
__global__ __launch_bounds__(256) void k_attn(const bf* __restrict__ Qn,  // [B*H,S,64]
                                              const bf* __restrict__ Kn,  // [B*H,S,64]
                                              const bf* __restrict__ Vt,  // [B*H,64,S]
                                              bf* __restrict__ Ctx) {     // [B*S, D]
    __shared__ __align__(16) bf Ksm[2][64 * 64];  // [kv][d], 16KB
    __shared__ __align__(16) bf Vsm[2][64 * 64];  // [d][kv], 16KB

    const int idx = blockIdx.x;
    const int qt = 31 - (idx >> 5);       // 0..31, largest-first (LPT)
    const int by = idx & 31;              // b*H + h
    const int b = by >> 4, h = by & 15;
    const int tid = threadIdx.x;
    const int w = tid >> 6, lane = tid & 63;
    const int l31 = lane & 31, hl = lane >> 5;
    const int qh = w >> 1;                // q-half: rows qt*64+qh*32 ..+32
    const int kp = w & 1;                 // k-parity: handles subtile kb=t*64+kp*32
    const int qw = qt * 64 + qh * 32;
    const int qg = qw + l31;

    const bf* Qp = Qn + (size_t)by * SS * 64;
    const bf* Kp = Kn + (size_t)by * SS * 64;
    const bf* Vp = Vt + (size_t)by * 64 * SS;

    // hoisted Q (B-operand): col=q=l31, d = st*16 + hl*8 + 0..7
    bf16x8 aqs[4];
#pragma unroll
    for (int st = 0; st < 4; ++st)
        aqs[st] = __builtin_bit_cast(bf16x8,
            *(const int4*)(Qp + (size_t)(qw + l31) * 64 + st * 16 + hl * 8));

    // staging: chunk c = 8 rows x 128B; pre-swizzled source slot
    const int srow = lane >> 3;
    const int sblk = (lane & 7) ^ srow;

    auto stage = [&](int buf, int k0) {
#pragma unroll
        for (int u = 0; u < 2; ++u) {
            const int c = w * 2 + u;
            const int row = c * 8 + srow;
            glds16(Kp + (size_t)(k0 + row) * 64 + sblk * 8, &Ksm[buf][c * 512]);
            glds16(Vp + (size_t)row * SS + k0 + sblk * 8, &Vsm[buf][c * 512]);
        }
    };

    f32x16 accd[2] = {};

    stage(0, 0);
    __syncthreads();
    int cur = 0;
    for (int t = 0; t <= qt; ++t) {
        if (t < qt) stage(cur ^ 1, (t + 1) * 64);
        const int kb = t * 64 + kp * 32;
        if (kb <= qw + 31) {
            // ---- QK^T (swapped): D[row=k][col=q]
            f32x16 pc = {};
#pragma unroll
            for (int st = 0; st < 4; ++st) {
                const int r = kp * 32 + l31;
                bf16x8 ak = __builtin_bit_cast(bf16x8,
                    *(const int4*)&Ksm[cur][r * 64 + (((2 * st + hl) ^ (r & 7)) << 3)]);
                pc = mfma32(ak, aqs[st], pc);
            }
            // ---- relu + causal (elementwise only near diagonal)
            const bool dg = (kb + 31 > qw);
            float pv[16];
#pragma unroll
            for (int m2 = 0; m2 < 16; ++m2) {
                float v = fmaxf(pc[m2], 0.0f);
                if (dg) {
                    const int kg = kb + (m2 & 3) + 8 * (m2 >> 2) + 4 * hl;
                    if (kg > qg) v = 0.0f;
                }
                pv[m2] = v;
            }
            // ---- pack to bf16 pairs + permlane swaps -> PV A-frags (no LDS)
            unsigned P[8];
#pragma unroll
            for (int m2 = 0; m2 < 8; ++m2) P[m2] = cvt_pk_bf16(pv[2 * m2], pv[2 * m2 + 1]);
            pl32swap(P[0], P[2]);
            pl32swap(P[1], P[3]);
            pl32swap(P[4], P[6]);
            pl32swap(P[5], P[7]);
            // ---- PV: D[row=q][col=d]
#pragma unroll
            for (int s = 0; s < 2; ++s) {
                uint4 pw = {P[4 * s + 0], P[4 * s + 1], P[4 * s + 2], P[4 * s + 3]};
                bf16x8 pa = __builtin_bit_cast(bf16x8, pw);
#pragma unroll
                for (int dt = 0; dt < 2; ++dt) {
                    const int d = dt * 32 + l31;
                    const int slot = kp * 4 + s * 2 + hl;
                    bf16x8 bv = __builtin_bit_cast(bf16x8,
                        *(const int4*)&Vsm[cur][d * 64 + ((slot ^ (d & 7)) << 3)]);
                    accd[dt] = mfma32(pa, bv, accd[dt]);
                }
            }
        }
        __syncthreads();
        cur ^= 1;
    }

    // ---- cross-wave (k-parity) reduce via LDS, then kp==0 writes Ctx
    float* red = (float*)&Ksm[0][0];      // 16KB: 2 q-halves x 8KB
    if (kp == 1) {
#pragma unroll
        for (int dt = 0; dt < 2; ++dt)
#pragma unroll
            for (int m2 = 0; m2 < 16; ++m2)
                red[qh * 2048 + (dt * 16 + m2) * 64 + lane] = accd[dt][m2];
    }
    __syncthreads();
    if (kp == 0) {
#pragma unroll
        for (int dt = 0; dt < 2; ++dt)
#pragma unroll
            for (int m2 = 0; m2 < 16; ++m2) {
                const float v = accd[dt][m2] + red[qh * 2048 + (dt * 16 + m2) * 64 + lane];
                const int q = qw + (m2 & 3) + 8 * (m2 >> 2) + 4 * hl;
                const int d = dt * 32 + l31;
                Ctx[(size_t)(b * SS + q) * DD + h * 64 + d] = __float2bfloat16(v);
            }
    }
}

// ---------------------------------------------------------------
extern "C" void kernel_launch(void* const* d_in, const int* in_sizes, int n_in,
                              void* d_out, int out_size, void* d_ws, size_t ws_size,
                              hipStream_t stream) {
    const float* X  = (const float*)d_in[0];
    const int* masks = (const int*)d_in[1];
    const float* Wq = (const float*)d_in[2];
    const float* Wk = (const float*)d_in[3];
    const float* Wv = (const float*)d_in[4];
    const float* Wo = (const float*)d_in[5];
    float* out = (float*)d_out;
    char* ws = (char*)d_ws;

    const size_t MB = 1024 * 1024;
    bf* Xb   = (bf*)(ws);              // 8 MB  [B*S, D]
    bf* Wqkv = (bf*)(ws + 8  * MB);    // 6 MB  [3072, 1024]
    bf* Wob  = (bf*)(ws + 14 * MB);    // 2 MB
    bf* Qn   = (bf*)(ws + 16 * MB);    // 8 MB  [B*H, S, 64]
    bf* Kn   = (bf*)(ws + 24 * MB);
    bf* Vt   = (bf*)(ws + 32 * MB);    // 8 MB  [B*H, 64, S]
    bf* Ctx  = (bf*)(ws + 40 * MB);    // 8 MB  [B*S, D]

    // converts (one launch)
    k_convert<<<8192, 256, 0, stream>>>(X, Wq, Wk, Wv, Wo, Xb, Wqkv, Wob);

    // fused QKV projection + norm/mask epilogue + V-transpose
    // 128x256 tiles -> (4096/128)*(3072/256) = 32*12 = 384 blocks, 8 waves
    k_gemmq<<<(MMR / 128) * (ND3 / 256), 512, 0, stream>>>(
        Xb, Wqkv, masks, Qn, Kn, Vt, ND3 / 256, DD);

    // attention (r4 structure: 2-buffer, 1024 blocks)
    k_attn<<<1024, 256, 0, stream>>>(Qn, Kn, Vt, Ctx);

    // output projection (64x128 tiles -> 512 blocks)
    k_gemm<<<(DD / 128) * (MMR / 64), 256, 0, stream>>>(
        Ctx, Wob, out, DD / 128, DD, DD);
}

// Round 10
// 102.326 us; speedup vs baseline: 1.3768x; 1.0177x over previous
//
#include <hip/hip_runtime.h>
#include <hip/hip_bf16.h>

// Problem constants
#define BB 2
#define SS 2048
#define DD 1024
#define HH 16
#define MMR (BB*SS)   // 4096 rows
#define ND3 3072      // fused QKV width

typedef __hip_bfloat16 bf;
typedef __bf16 bf16x8 __attribute__((ext_vector_type(8)));
typedef float f32x4 __attribute__((ext_vector_type(4)));
typedef float f32x16 __attribute__((ext_vector_type(16)));

#define VMCNT(n) asm volatile("s_waitcnt vmcnt(" #n ")" ::: "memory")

__device__ __forceinline__ f32x4 mfma16(bf16x8 a, bf16x8 b, f32x4 c) {
    return __builtin_amdgcn_mfma_f32_16x16x32_bf16(a, b, c, 0, 0, 0);
}
__device__ __forceinline__ f32x16 mfma32(bf16x8 a, bf16x8 b, f32x16 c) {
    return __builtin_amdgcn_mfma_f32_32x32x16_bf16(a, b, c, 0, 0, 0);
}
__device__ __forceinline__ unsigned cvt_pk_bf16(float lo, float hi) {
    unsigned r;
    asm("v_cvt_pk_bf16_f32 %0, %1, %2" : "=v"(r) : "v"(lo), "v"(hi));
    return r;
}
// after: a = {a.lo31, b.lo31}, b = {a.hi31, b.hi31}
__device__ __forceinline__ void pl32swap(unsigned& a, unsigned& b) {
    asm("v_permlane32_swap_b32 %0, %1" : "+v"(a), "+v"(b));
}
// async global->LDS, 16B/lane; LDS dest = wave-uniform base + lane*16
__device__ __forceinline__ void glds16(const bf* g, bf* l) {
    __builtin_amdgcn_global_load_lds(
        (const __attribute__((address_space(1))) void*)g,
        (__attribute__((address_space(3))) void*)l,
        16, 0, 0);
}

// ---------------------------------------------------------------
// All f32->bf16 converts in ONE launch. blocks 0..4095: X (4M elems);
// blocks 4096..8191: Wq,Wk,Wv (into Wqkv) and Wo (into Wob), 1M each.
__global__ __launch_bounds__(256) void k_convert(const float* __restrict__ X,
                                                 const float* __restrict__ Wq,
                                                 const float* __restrict__ Wk,
                                                 const float* __restrict__ Wv,
                                                 const float* __restrict__ Wo,
                                                 bf* __restrict__ Xb,
                                                 bf* __restrict__ Wqkv,
                                                 bf* __restrict__ Wob) {
    const int bid = blockIdx.x;
    const float* src;
    bf* dst;
    int off;
    if (bid < 4096) {
        src = X; dst = Xb; off = bid;
    } else {
        const int r = (bid - 4096) >> 10;
        src = (r == 0) ? Wq : (r == 1) ? Wk : (r == 2) ? Wv : Wo;
        dst = (r < 3) ? (Wqkv + (size_t)r * 1048576) : Wob;
        off = (bid - 4096) & 1023;
    }
    const int j = (off * 256 + threadIdx.x) * 4;
    float4 v = *(const float4*)(src + j);
    bf tmp[4];
    tmp[0] = __float2bfloat16(v.x);
    tmp[1] = __float2bfloat16(v.y);
    tmp[2] = __float2bfloat16(v.z);
    tmp[3] = __float2bfloat16(v.w);
    *(uint2*)(dst + j) = *(const uint2*)tmp;
}

// ---------------------------------------------------------------
// QKV GEMM (r7-proven best, ~37us): 128x128 tile, BK=32, 8 waves (512 thr),
// wave = 32x64 quadrant (8 MFMA/step). 3-buffer LDS pipeline, counted vmcnt,
// raw s_barrier, seg-XOR LDS swizzle (0-conflict). 768 blocks x 8 waves =
// 3 blocks/CU = 24 waves/CU: wave-parallelism is the lever in this
// latency-bound short-K regime (r4/r5/r7/r9 evidence).
// Fused epilogue: cols<2048 -> per-head L2-norm * mask -> Qn/Kn [B*H,S,64];
// cols>=2048 -> transposed bf16 write to Vt [B*H,64,S].
__global__ __launch_bounds__(512, 6) void k_gemm8(const bf* __restrict__ A,
                                                  const bf* __restrict__ Bt,
                                                  const int* __restrict__ masks,
                                                  bf* __restrict__ Qn,
                                                  bf* __restrict__ Kn,
                                                  bf* __restrict__ Vt,
                                                  int nx, int K) {
    __shared__ __align__(16) bf Asm[3][128 * 32];
    __shared__ __align__(16) bf Bsm[3][128 * 32];
    const int tid = threadIdx.x;
    const int w = tid >> 6, lane = tid & 63, g = lane >> 4, rl = lane & 15;
    const int cpx = gridDim.x >> 3;
    const int swz = (blockIdx.x & 7) * cpx + (blockIdx.x >> 3);
    const int m0 = (swz / nx) * 128, n0 = (swz % nx) * 128;
    const int wr = (w >> 1) * 32, wc = (w & 1) * 64;
    const int lrow = lane >> 2, lseg = lane & 3;
    const int xseg = lseg ^ ((lrow >> 1) & 3);   // pre-swizzled source seg

    f32x4 acc[2][4] = {};
    const bf* Ap = A + (size_t)m0 * K;
    const bf* Bp = Bt + (size_t)n0 * K;

    auto stage = [&](int bi, int k0) {
        glds16(Ap + (size_t)(w * 16 + lrow) * K + k0 + xseg * 8, &Asm[bi][w * 512]);
        glds16(Bp + (size_t)(w * 16 + lrow) * K + k0 + xseg * 8, &Bsm[bi][w * 512]);
    };

    const int T = K >> 5;
    stage(0, 0);
    stage(1, 32);
    int cur = 0, nxt = 2;
    for (int t = 0; t < T; ++t) {
        __builtin_amdgcn_sched_barrier(0);
        if (t < T - 1) { VMCNT(2); } else { VMCNT(0); }
        __builtin_amdgcn_s_barrier();     // staged loads stay in flight
        __builtin_amdgcn_sched_barrier(0);
        if (t + 2 < T) stage(nxt, (t + 2) * 32);

        const bf* Ab = Asm[cur];
        const bf* Bb = Bsm[cur];
        bf16x8 af[2], bfr[4];
#pragma unroll
        for (int m = 0; m < 2; ++m) {
            const int row = wr + m * 16 + rl;
            af[m] = __builtin_bit_cast(bf16x8,
                *(const int4*)&Ab[row * 32 + (g ^ ((row >> 1) & 3)) * 8]);
        }
#pragma unroll
        for (int n = 0; n < 4; ++n) {
            const int row = wc + n * 16 + rl;
            bfr[n] = __builtin_bit_cast(bf16x8,
                *(const int4*)&Bb[row * 32 + (g ^ ((row >> 1) & 3)) * 8]);
        }
        __builtin_amdgcn_s_setprio(1);
#pragma unroll
        for (int m = 0; m < 2; ++m)
#pragma unroll
            for (int n = 0; n < 4; ++n)
                acc[m][n] = mfma16(af[m], bfr[n], acc[m][n]);
        __builtin_amdgcn_s_setprio(0);

        cur = (cur == 2) ? 0 : cur + 1;
        nxt = (nxt == 2) ? 0 : nxt + 1;
    }

    const int ncol0 = n0 + wc;   // wave's 64-col base == one head slice
    if (ncol0 < 2048) {
        bf* dst = (ncol0 < 1024) ? Qn : Kn;
        const int h2 = (ncol0 >> 6) & 15;
#pragma unroll
        for (int m = 0; m < 2; ++m) {
#pragma unroll
            for (int ri = 0; ri < 4; ++ri) {
                const int row = m0 + wr + m * 16 + g * 4 + ri;   // b*S+s
                float ss = 0.f;
#pragma unroll
                for (int n = 0; n < 4; ++n) ss += acc[m][n][ri] * acc[m][n][ri];
#pragma unroll
                for (int d = 1; d < 16; d <<= 1) ss += __shfl_xor(ss, d, 64);
                const float sc = rsqrtf(ss) * (masks[row] ? 1.0f : 0.0f);
                const int b = row >> 11, s = row & 2047;
                const size_t base = ((size_t)(b * HH + h2) * SS + s) * 64;
#pragma unroll
                for (int n = 0; n < 4; ++n)
                    dst[base + n * 16 + rl] = __float2bfloat16(acc[m][n][ri] * sc);
            }
        }
    } else {
        // fused V transpose: Vt[(b*H+h)*64 + d][s], packed 4-bf16 writes
        const int h2 = (ncol0 - 2048) >> 6;
        const int b = (m0 + wr) >> 11;
        const int sb = ((m0 + wr) & 2047) + g * 4;
#pragma unroll
        for (int m = 0; m < 2; ++m)
#pragma unroll
            for (int n = 0; n < 4; ++n) {
                const int d = n * 16 + rl;
                bf t4[4];
#pragma unroll
                for (int ri = 0; ri < 4; ++ri) t4[ri] = __float2bfloat16(acc[m][n][ri]);
                *(uint2*)&Vt[((size_t)(b * HH + h2) * 64 + d) * SS + sb + m * 16] =
                    *(uint2*)t4;
            }
    }
}

// ---------------------------------------------------------------
// Out-proj GEMM: 64x128 tile, BK=32, 4 waves, 3-buffer counted-vmcnt pipeline.
__global__ __launch_bounds__(256) void k_gemm(const bf* __restrict__ A,
                                              const bf* __restrict__ Bt,
                                              float* __restrict__ Cf,
                                              int nx, int N, int K) {
    constexpr int BM = 64, BN = 128;
    __shared__ __align__(16) bf Asm[3][BM * 32];
    __shared__ __align__(16) bf Bsm[3][BN * 32];
    const int tid = threadIdx.x;
    const int w = tid >> 6, lane = tid & 63, g = lane >> 4, rl = lane & 15;
    const int cpx = gridDim.x >> 3;
    const int swz = (blockIdx.x & 7) * cpx + (blockIdx.x >> 3);
    const int m0 = (swz / nx) * BM, n0 = (swz % nx) * BN;
    const int wr = (w >> 1) * 32, wc = (w & 1) * 64;
    const int lrow = lane >> 2, lseg = lane & 3;
    const int xseg = lseg ^ ((lrow >> 1) & 3);

    f32x4 acc[2][4] = {};
    const bf* Ap = A + (size_t)m0 * K;
    const bf* Bp = Bt + (size_t)n0 * K;

    auto stage = [&](int bi, int k0) {
        glds16(Ap + (size_t)(w * 16 + lrow) * K + k0 + xseg * 8, &Asm[bi][w * 512]);
#pragma unroll
        for (int u = 0; u < 2; ++u)
            glds16(Bp + (size_t)(u * 64 + w * 16 + lrow) * K + k0 + xseg * 8,
                   &Bsm[bi][(u * 64 + w * 16) * 32]);
    };

    const int T = K >> 5;
    stage(0, 0);
    stage(1, 32);
    int cur = 0, nxt = 2;
    for (int t = 0; t < T; ++t) {
        __builtin_amdgcn_sched_barrier(0);
        if (t < T - 1) { VMCNT(3); } else { VMCNT(0); }
        __builtin_amdgcn_s_barrier();
        __builtin_amdgcn_sched_barrier(0);
        if (t + 2 < T) stage(nxt, (t + 2) * 32);

        const bf* Ab = Asm[cur];
        const bf* Bb = Bsm[cur];
        bf16x8 af[2], bfr[4];
#pragma unroll
        for (int m = 0; m < 2; ++m) {
            const int row = wr + m * 16 + rl;
            af[m] = __builtin_bit_cast(bf16x8,
                *(const int4*)&Ab[row * 32 + (g ^ ((row >> 1) & 3)) * 8]);
        }
#pragma unroll
        for (int n = 0; n < 4; ++n) {
            const int row = wc + n * 16 + rl;
            bfr[n] = __builtin_bit_cast(bf16x8,
                *(const int4*)&Bb[row * 32 + (g ^ ((row >> 1) & 3)) * 8]);
        }
        __builtin_amdgcn_s_setprio(1);
#pragma unroll
        for (int m = 0; m < 2; ++m)
#pragma unroll
            for (int n = 0; n < 4; ++n)
                acc[m][n] = mfma16(af[m], bfr[n], acc[m][n]);
        __builtin_amdgcn_s_setprio(0);

        cur = (cur == 2) ? 0 : cur + 1;
        nxt = (nxt == 2) ? 0 : nxt + 1;
    }

#pragma unroll
    for (int m = 0; m < 2; ++m)
#pragma unroll
        for (int n = 0; n < 4; ++n)
#pragma unroll
            for (int ri = 0; ri < 4; ++ri)
                Cf[(size_t)(m0 + wr + m * 16 + g * 4 + ri) * N + n0 + wc + n * 16 + rl] =
                    acc[m][n][ri];
}

// ---------------------------------------------------------------
// Attention (r4-proven structure, ~28us): 32x32 MFMA + in-register P (T12),
// q-tile 64, 1024 blocks (LPT). 4 waves = (q-half qh) x (k-parity kp).
// 2-buffer K/V staged via glds16 (XOR-swizzled source), single __syncthreads
// per tile (stage next -> compute current -> sync). Partial O's summed via
// one-time LDS reduce (no softmax -> plain add).
__global__ __launch_bounds__(256) void k_attn(const bf* __restrict__ Qn,  // [B*H,S,64]
                                              const bf* __restrict__ Kn,  // [B*H,S,64]
                                              const bf* __restrict__ Vt,  // [B*H,64,S]
                                              bf* __restrict__ Ctx) {     // [B*S, D]
    __shared__ __align__(16) bf Ksm[2][64 * 64];  // [kv][d], 16KB
    __shared__ __align__(16) bf Vsm[2][64 * 64];  // [d][kv], 16KB

    const int idx = blockIdx.x;
    const int qt = 31 - (idx >> 5);       // 0..31, largest-first (LPT)
    const int by = idx & 31;              // b*H + h
    const int b = by >> 4, h = by & 15;
    const int tid = threadIdx.x;
    const int w = tid >> 6, lane = tid & 63;
    const int l31 = lane & 31, hl = lane >> 5;
    const int qh = w >> 1;                // q-half: rows qt*64+qh*32 ..+32
    const int kp = w & 1;                 // k-parity: handles subtile kb=t*64+kp*32
    const int qw = qt * 64 + qh * 32;
    const int qg = qw + l31;

    const bf* Qp = Qn + (size_t)by * SS * 64;
    const bf* Kp = Kn + (size_t)by * SS * 64;
    const bf* Vp = Vt + (size_t)by * 64 * SS;

    // hoisted Q (B-operand): col=q=l31, d = st*16 + hl*8 + 0..7
    bf16x8 aqs[4];
#pragma unroll
    for (int st = 0; st < 4; ++st)
        aqs[st] = __builtin_bit_cast(bf16x8,
            *(const int4*)(Qp + (size_t)(qw + l31) * 64 + st * 16 + hl * 8));

    // staging: chunk c = 8 rows x 128B; pre-swizzled source slot
    const int srow = lane >> 3;
    const int sblk = (lane & 7) ^ srow;

    auto stage = [&](int buf, int k0) {
#pragma unroll
        for (int u = 0; u < 2; ++u) {
            const int c = w * 2 + u;
            const int row = c * 8 + srow;
            glds16(Kp + (size_t)(k0 + row) * 64 + sblk * 8, &Ksm[buf][c * 512]);
            glds16(Vp + (size_t)row * SS + k0 + sblk * 8, &Vsm[buf][c * 512]);
        }
    };

    f32x16 accd[2] = {};

    stage(0, 0);
    __syncthreads();
    int cur = 0;
    for (int t = 0; t <= qt; ++t) {
        if (t < qt) stage(cur ^ 1, (t + 1) * 64);
        const int kb = t * 64 + kp * 32;
        if (kb <= qw + 31) {
            // ---- QK^T (swapped): D[row=k][col=q]
            f32x16 pc = {};
#pragma unroll
            for (int st = 0; st < 4; ++st) {
                const int r = kp * 32 + l31;
                bf16x8 ak = __builtin_bit_cast(bf16x8,
                    *(const int4*)&Ksm[cur][r * 64 + (((2 * st + hl) ^ (r & 7)) << 3)]);
                pc = mfma32(ak, aqs[st], pc);
            }
            // ---- relu + causal (elementwise only near diagonal)
            const bool dg = (kb + 31 > qw);
            float pv[16];
#pragma unroll
            for (int m2 = 0; m2 < 16; ++m2) {
                float v = fmaxf(pc[m2], 0.0f);
                if (dg) {
                    const int kg = kb + (m2 & 3) + 8 * (m2 >> 2) + 4 * hl;
                    if (kg > qg) v = 0.0f;
                }
                pv[m2] = v;
            }
            // ---- pack to bf16 pairs + permlane swaps -> PV A-frags (no LDS)
            unsigned P[8];
#pragma unroll
            for (int m2 = 0; m2 < 8; ++m2) P[m2] = cvt_pk_bf16(pv[2 * m2], pv[2 * m2 + 1]);
            pl32swap(P[0], P[2]);
            pl32swap(P[1], P[3]);
            pl32swap(P[4], P[6]);
            pl32swap(P[5], P[7]);
            // ---- PV: D[row=q][col=d]
#pragma unroll
            for (int s = 0; s < 2; ++s) {
                uint4 pw = {P[4 * s + 0], P[4 * s + 1], P[4 * s + 2], P[4 * s + 3]};
                bf16x8 pa = __builtin_bit_cast(bf16x8, pw);
#pragma unroll
                for (int dt = 0; dt < 2; ++dt) {
                    const int d = dt * 32 + l31;
                    const int slot = kp * 4 + s * 2 + hl;
                    bf16x8 bv = __builtin_bit_cast(bf16x8,
                        *(const int4*)&Vsm[cur][d * 64 + ((slot ^ (d & 7)) << 3)]);
                    accd[dt] = mfma32(pa, bv, accd[dt]);
                }
            }
        }
        __syncthreads();
        cur ^= 1;
    }

    // ---- cross-wave (k-parity) reduce via LDS, then kp==0 writes Ctx
    float* red = (float*)&Ksm[0][0];      // 16KB: 2 q-halves x 8KB
    if (kp == 1) {
#pragma unroll
        for (int dt = 0; dt < 2; ++dt)
#pragma unroll
            for (int m2 = 0; m2 < 16; ++m2)
                red[qh * 2048 + (dt * 16 + m2) * 64 + lane] = accd[dt][m2];
    }
    __syncthreads();
    if (kp == 0) {
#pragma unroll
        for (int dt = 0; dt < 2; ++dt)
#pragma unroll
            for (int m2 = 0; m2 < 16; ++m2) {
                const float v = accd[dt][m2] + red[qh * 2048 + (dt * 16 + m2) * 64 + lane];
                const int q = qw + (m2 & 3) + 8 * (m2 >> 2) + 4 * hl;
                const int d = dt * 32 + l31;
                Ctx[(size_t)(b * SS + q) * DD + h * 64 + d] = __float2bfloat16(v);
            }
    }
}

// ---------------------------------------------------------------
extern "C" void kernel_launch(void* const* d_in, const int* in_sizes, int n_in,
                              void* d_out, int out_size, void* d_ws, size_t ws_size,
                              hipStream_t stream) {
    const float* X  = (const float*)d_in[0];
    const int* masks = (const int*)d_in[1];
    const float* Wq = (const float*)d_in[2];
    const float* Wk = (const float*)d_in[3];
    const float* Wv = (const float*)d_in[4];
    const float* Wo = (const float*)d_in[5];
    float* out = (float*)d_out;
    char* ws = (char*)d_ws;

    const size_t MB = 1024 * 1024;
    bf* Xb   = (bf*)(ws);              // 8 MB  [B*S, D]
    bf* Wqkv = (bf*)(ws + 8  * MB);    // 6 MB  [3072, 1024]
    bf* Wob  = (bf*)(ws + 14 * MB);    // 2 MB
    bf* Qn   = (bf*)(ws + 16 * MB);    // 8 MB  [B*H, S, 64]
    bf* Kn   = (bf*)(ws + 24 * MB);
    bf* Vt   = (bf*)(ws + 32 * MB);    // 8 MB  [B*H, 64, S]
    bf* Ctx  = (bf*)(ws + 40 * MB);    // 8 MB  [B*S, D]

    // converts (one launch)
    k_convert<<<8192, 256, 0, stream>>>(X, Wq, Wk, Wv, Wo, Xb, Wqkv, Wob);

    // fused QKV projection + norm/mask epilogue + V-transpose
    // (128x128 tiles -> 768 blocks, 8 waves: r7-proven best)
    k_gemm8<<<(ND3 / 128) * (MMR / 128), 512, 0, stream>>>(
        Xb, Wqkv, masks, Qn, Kn, Vt, ND3 / 128, DD);

    // attention (r4 structure: 2-buffer, 1024 blocks)
    k_attn<<<1024, 256, 0, stream>>>(Qn, Kn, Vt, Ctx);

    // output projection (64x128 tiles -> 512 blocks)
    k_gemm<<<(DD / 128) * (MMR / 64), 256, 0, stream>>>(
        Ctx, Wob, out, DD / 128, DD, DD);
}